// Round 14
// baseline (59.349 us; speedup 1.0000x reference)
//
#include <hip/hip_runtime.h>
#include <hip/hip_bf16.h>
#include <stdint.h>

#define DD 128
#define CC 16
#define NS 1600
#define QQ 32768
#define NBLK 64

typedef __attribute__((ext_vector_type(8))) short short8;   // 8 bf16
typedef __attribute__((ext_vector_type(4))) short short4v;  // 4 bf16
typedef __attribute__((ext_vector_type(4))) float f32x4;

__device__ inline short f2bf(float x) {
  union { float f; uint32_t u; } v; v.f = x;
  uint32_t r = (v.u + 0x7FFFu + ((v.u >> 16) & 1u)) >> 16;  // RNE
  return (short)r;
}

__device__ inline uint32_t pk2bf(float lo, float hi) {
  __hip_bfloat162 h = __float22bfloat162_rn(make_float2(lo, hi));  // lo->low16
  union { __hip_bfloat162 h2; uint32_t u; } v; v.h2 = h;
  return v.u;
}

__device__ inline float bfbits2f(uint32_t hi16bits) {
  union { uint32_t u; float f; } v; v.u = hi16bits;
  return v.f;
}

// ---------------------------------------------------------------------------
// Kernel 1: fused prep. grid=320, block=256. (identical to R13)
// ---------------------------------------------------------------------------
__global__ __launch_bounds__(256) void prep_kernel(
    const float* __restrict__ sfi, const float* __restrict__ sf,
    const int* __restrict__ labels, const float* __restrict__ qf,
    float* __restrict__ partA, float* __restrict__ partB,
    float* __restrict__ pcnt, short* __restrict__ qbf) {
  const int t = threadIdx.x;

  if (blockIdx.x >= NBLK) {  // ---- q conversion: 128 rows per block ----
    const size_t cb = (size_t)(blockIdx.x - NBLK) * (128 * DD);
#pragma unroll
    for (int i = 0; i < 16; ++i) {
      const size_t off = cb + ((size_t)i * 256 + t) * 4;
      f32x4 f = *(const f32x4*)(qf + off);
      union { short4v s; uint32_t u[2]; } r;
      r.u[0] = pk2bf(f[0], f[1]);
      r.u[1] = pk2bf(f[2], f[3]);
      *(short4v*)(qbf + off) = r.s;
    }
    return;
  }

  // ---- centers partials ----
  __shared__ float accA[2][CC][DD];
  __shared__ float accB[2][CC][DD];
  __shared__ float cnt[2][CC];
  const int d = t & 127, s = t >> 7;
  for (int i = t; i < 2 * CC * DD; i += 256) {
    ((float*)accA)[i] = 0.f;
    ((float*)accB)[i] = 0.f;
  }
  if (t < 2 * CC) ((float*)cnt)[t] = 0.f;
  __syncthreads();

  const int base = blockIdx.x * (NS / NBLK);
  for (int i = s; i < NS / NBLK; i += 2) {
    const int r = base + i;
    const int lbl = labels[r];
    accA[s][lbl][d] += sfi[(size_t)r * DD + d];
    accB[s][lbl][d] += sf[(size_t)r * DD + d];
    if (d == 0) cnt[s][lbl] += 1.f;
  }
  __syncthreads();

  float* pa = partA + (size_t)blockIdx.x * (CC * DD);
  float* pb = partB + (size_t)blockIdx.x * (CC * DD);
  for (int i = t; i < CC * DD; i += 256) {
    pa[i] = ((float*)accA)[i] + ((float*)accA)[CC * DD + i];
    pb[i] = ((float*)accB)[i] + ((float*)accB)[CC * DD + i];
  }
  if (t < CC) pcnt[blockIdx.x * CC + t] = cnt[0][t] + cnt[1][t];
}

// ---------------------------------------------------------------------------
// Kernel 2: finalize centers + fused per-class weights in FRAGMENT order.
// 16B unit u within class c: u = w*256 + kb*64 + lane (w=0..7, kb=0..3)
//   holds WtT[j][e0..e0+7] bf16, j = w*16 + (lane&15), e0 = kb*32 + (lane>>4)*8
// grid=16 (c), block=256. (identical to R13 -- main depends on layout)
// ---------------------------------------------------------------------------
__global__ __launch_bounds__(256) void build_wt_kernel(
    const float* __restrict__ W1, const float* __restrict__ partA,
    const float* __restrict__ partB, const float* __restrict__ pcnt,
    float* __restrict__ sg_out, short* __restrict__ WtTg) {
  __shared__ float sgc[DD], prc[DD];
  const int c = blockIdx.x, t = threadIdx.x;

  float cnt = 0.f;
  for (int b = 0; b < NBLK; ++b) cnt += pcnt[b * CC + c];
  cnt = fmaxf(cnt, 1.f);
  if (t < 128) {
    float a = 0.f;
    for (int b = 0; b < NBLK; ++b) a += partA[(size_t)b * (CC * DD) + c * DD + t];
    const float m = a / cnt;
    const float s = 1.f / (1.f + expf(-m));
    sgc[t] = s;
    sg_out[c * DD + t] = s;
  } else {
    const int d = t - 128;
    float a = 0.f;
    for (int b = 0; b < NBLK; ++b) a += partB[(size_t)b * (CC * DD) + c * DD + d];
    prc[d] = a / cnt;
  }
  __syncthreads();

  for (int it = 0; it < 8; ++it) {
    const int u = it * 256 + t;
    const int w_ = u >> 8;
    const int kb = (u >> 6) & 3;
    const int lane = u & 63;
    const int j = w_ * 16 + (lane & 15);
    const int e0 = kb * 32 + (lane >> 4) * 8;
    short8 r;
#pragma unroll
    for (int rr = 0; rr < 8; ++rr) {
      const int e = e0 + rr;
      float v = W1[e * DD + j] + sgc[e] * W1[(DD + e) * DD + j] +
                prc[e] * W1[2 * DD * DD + j];
      r[rr] = f2bf(v);
    }
    *(short8*)(WtTg + ((size_t)c * 2048 + u) * 8) = r;
  }
}

// ---------------------------------------------------------------------------
// Kernel 3: FUSED main, HIGH-OCCUPANCY variant. grid=1024, block=512
// (8 waves), 32 q/block. Wave w: j rows [w*16,+16), all 32 q.
// bq[2][4]=32 VGPR (live set ~95 -> no AGPR demotion, ~20 waves/SIMD cap);
// LDS 18.6 KB -> 4 blocks/CU = 32 waves/CU. Class-order rotation per block
// (phase = blockIdx&15) de-contends the shared 512KB W-set in L2.
// p_pln[16][8][32] holds ALL classes -> ZERO barriers in class loop;
// one barrier, REDUCE (512 thr, 1:1), fused agg epilogue.
// ---------------------------------------------------------------------------
__global__ __launch_bounds__(512) void main_kernel(
    const short* __restrict__ qbf, const short* __restrict__ WtTg,
    const float* __restrict__ b1, const float* __restrict__ W2,
    const float* __restrict__ b2, const float* __restrict__ sg,
    float* __restrict__ out) {
  __shared__ float p_pln[CC][8][32];  // [cls][w][q] 16 KB
  __shared__ float w_lds[32][17];     // [q][c], padded, 2.2 KB

  const int tid = threadIdx.x;
  const int lane = tid & 63;
  const int w = tid >> 6;  // 0..7
  const int l15 = lane & 15, l4 = lane >> 4;
  const int qbase = blockIdx.x * 32;
  const int phase = blockIdx.x & 15;

  // ---- B fragments: direct bf16 loads, 2 qn x 4 kb = 32 VGPR ----
  short8 bq[2][4];
#pragma unroll
  for (int qn = 0; qn < 2; ++qn) {
    const short* qrow = qbf + (size_t)(qbase + qn * 16 + l15) * DD;
#pragma unroll
    for (int kb = 0; kb < 4; ++kb)
      bq[qn][kb] = *(const short8*)(qrow + kb * 32 + l4 * 8);
  }

  const f32x4 b1v = *(const f32x4*)(b1 + w * 16 + l4 * 4);
  const f32x4 w2v = *(const f32x4*)(W2 + w * 16 + l4 * 4);
  const float b2s = b2[0];

  const char* wbase = (const char*)WtTg + w * 4096 + lane * 16;

#define LOADW(dst, cc)                                                      \
  {                                                                         \
    _Pragma("unroll") for (int kb = 0; kb < 4; ++kb) dst[kb] =              \
        *(const short8*)(wbase + (size_t)(cc)*32768 + kb * 1024);           \
  }

#define COMPUTE(wf, cc)                                                     \
  {                                                                         \
    f32x4 a0 = b1v, a1 = b1v;                                               \
    _Pragma("unroll") for (int kb = 0; kb < 4; ++kb) {                      \
      a0 = __builtin_amdgcn_mfma_f32_16x16x32_bf16(wf[kb], bq[0][kb], a0,   \
                                                   0, 0, 0);                \
      a1 = __builtin_amdgcn_mfma_f32_16x16x32_bf16(wf[kb], bq[1][kb], a1,   \
                                                   0, 0, 0);                \
    }                                                                       \
    float p0 = 0.f, p1 = 0.f;                                               \
    _Pragma("unroll") for (int i = 0; i < 4; ++i) {                         \
      p0 += fmaxf(a0[i], 0.f) * w2v[i];                                     \
      p1 += fmaxf(a1[i], 0.f) * w2v[i];                                     \
    }                                                                       \
    p0 += __shfl_xor(p0, 16);                                               \
    p0 += __shfl_xor(p0, 32);                                               \
    p1 += __shfl_xor(p1, 16);                                               \
    p1 += __shfl_xor(p1, 32);                                               \
    if (l4 == 0) {                                                          \
      p_pln[cc][w][l15] = p0;                                               \
      p_pln[cc][w][16 + l15] = p1;                                          \
    }                                                                       \
  }

  short8 wfA[4], wfB[4];
  // 2-buffer rotation, fully unrolled, rotated class order, NO barriers.
  LOADW(wfA, phase);
  LOADW(wfB, (phase + 1) & 15);  COMPUTE(wfA, phase);
  LOADW(wfA, (phase + 2) & 15);  COMPUTE(wfB, (phase + 1) & 15);
  LOADW(wfB, (phase + 3) & 15);  COMPUTE(wfA, (phase + 2) & 15);
  LOADW(wfA, (phase + 4) & 15);  COMPUTE(wfB, (phase + 3) & 15);
  LOADW(wfB, (phase + 5) & 15);  COMPUTE(wfA, (phase + 4) & 15);
  LOADW(wfA, (phase + 6) & 15);  COMPUTE(wfB, (phase + 5) & 15);
  LOADW(wfB, (phase + 7) & 15);  COMPUTE(wfA, (phase + 6) & 15);
  LOADW(wfA, (phase + 8) & 15);  COMPUTE(wfB, (phase + 7) & 15);
  LOADW(wfB, (phase + 9) & 15);  COMPUTE(wfA, (phase + 8) & 15);
  LOADW(wfA, (phase + 10) & 15); COMPUTE(wfB, (phase + 9) & 15);
  LOADW(wfB, (phase + 11) & 15); COMPUTE(wfA, (phase + 10) & 15);
  LOADW(wfA, (phase + 12) & 15); COMPUTE(wfB, (phase + 11) & 15);
  LOADW(wfB, (phase + 13) & 15); COMPUTE(wfA, (phase + 12) & 15);
  LOADW(wfA, (phase + 14) & 15); COMPUTE(wfB, (phase + 13) & 15);
  LOADW(wfB, (phase + 15) & 15); COMPUTE(wfA, (phase + 14) & 15);
  COMPUTE(wfB, (phase + 15) & 15);
#undef LOADW
#undef COMPUTE

  __syncthreads();  // the ONLY barrier

  // ---- REDUCE: 512 threads 1:1 over (cc, q) ----
  {
    const int cc = tid >> 5, rq = tid & 31;
    float s = 0.f;
#pragma unroll
    for (int wv = 0; wv < 8; ++wv) s += p_pln[cc][wv][rq];
    w_lds[rq][cc] = 1.f / (1.f + __expf(-(s + b2s)));
  }
  __syncthreads();

  // ---- fused agg epilogue: wave w -> q-slots qi*8+w (qi 0..3) ----
  {
    float2 sgv[16];  // 32 regs (bq dead by now)
#pragma unroll
    for (int c = 0; c < 16; ++c)
      sgv[c] = *(const float2*)(sg + c * DD + 2 * lane);

#pragma unroll
    for (int qi = 0; qi < 4; ++qi) {
      const int ql = qi * 8 + w;
      const int q = qbase + ql;
      float Sv = 0.f, swx = 0.f, swy = 0.f;
#pragma unroll
      for (int c = 0; c < 16; ++c) {
        const float wc = w_lds[ql][c];  // wave-uniform broadcast
        Sv += wc;
        swx += wc * sgv[c].x;
        swy += wc * sgv[c].y;
      }
      const uint16_t* row = (const uint16_t*)(qbf + (size_t)q * DD);
      const uint32_t pair = *(const uint32_t*)(row + 2 * lane);
      const float q0 = bfbits2f(pair << 16);
      const float q1 = bfbits2f(pair & 0xFFFF0000u);
      const float qlo = bfbits2f((uint32_t)row[lane] << 16);
      const float qhi = bfbits2f((uint32_t)row[64 + lane] << 16);

      float* orow = out + (size_t)q * DD;
      orow[lane] = 0.5f * (q0 + q1) * Sv + qlo;
      orow[64 + lane] = 0.5f * (q0 * swx + q1 * swy) + qhi;
    }
  }
}

// ---------------------------------------------------------------------------
extern "C" void kernel_launch(void* const* d_in, const int* in_sizes, int n_in,
                              void* d_out, int out_size, void* d_ws, size_t ws_size,
                              hipStream_t stream) {
  const float* sfi = (const float*)d_in[0];
  const float* sf  = (const float*)d_in[1];
  const float* qf  = (const float*)d_in[2];
  const float* W1  = (const float*)d_in[3];
  const float* b1  = (const float*)d_in[4];
  const float* W2  = (const float*)d_in[5];
  const float* b2  = (const float*)d_in[6];
  const int* slab  = (const int*)d_in[7];
  float* out = (float*)d_out;

  float* sg    = (float*)d_ws;                    // 2048 f
  short* WtTg  = (short*)(sg + CC * DD);          // 262144 shorts (512 KB)
  float* partA = (float*)(WtTg + CC * DD * DD);   // 64*2048 f
  float* partB = partA + NBLK * CC * DD;          // 64*2048 f
  float* pcnt  = partB + NBLK * CC * DD;          // 64*16 f
  short* qbf   = (short*)(pcnt + NBLK * CC);      // QQ*DD shorts (8 MB)

  prep_kernel<<<NBLK + QQ / 128, 256, 0, stream>>>(sfi, sf, slab, qf, partA,
                                                   partB, pcnt, qbf);
  build_wt_kernel<<<CC, 256, 0, stream>>>(W1, partA, partB, pcnt, sg, WtTg);
  main_kernel<<<QQ / 32, 512, 0, stream>>>(qbf, WtTg, b1, W2, b2, sg, out);
}